// Round 2
// baseline (759.222 us; speedup 1.0000x reference)
//
#include <hip/hip_runtime.h>
#include <math.h>

// TopKRouter: logits = x(16384x2048) @ W(2048x64) + b; softmax over E=64; top-2.
// Output layout: d_out[0:32768] = topk indices (as float), d_out[32768:65536] = topk probs.
//
// Structure: lane = expert (E=64 = wave width). Each wave independently owns
// ROWS_PER_WAVE rows. x[row][k] is wave-uniform -> s_load broadcast; W[k][lane]
// is a coalesced 256B/wave vector load, reused across all rows in-register.
// No LDS, no barriers.

#define D_DIM 2048
#define E_DIM 64
#define M_DIM 16384
#define RPW 8            // rows per wave
#define WPB 4            // waves per block
#define KU  8            // k unroll

__global__ __launch_bounds__(256, 2) void topk_router_kernel(
    const float* __restrict__ x, const float* __restrict__ Wm,
    const float* __restrict__ bias, float* __restrict__ out)
{
    const int lane = threadIdx.x & 63;
    // force wave-uniformity so x accesses scalarize to s_load
    const int wave = __builtin_amdgcn_readfirstlane(threadIdx.x >> 6);
    const int row0 = (blockIdx.x * WPB + wave) * RPW;

    const float* xb = x + (size_t)row0 * D_DIM;   // wave-uniform base
    const float* wp = Wm + lane;                  // per-lane W column

    float acc[RPW] = {};

    // double-buffered W registers: loads for k+KU issued before FMAs on k
    float wr[2][KU];
    #pragma unroll
    for (int u = 0; u < KU; u++)
        wr[0][u] = wp[(size_t)u * E_DIM];

    for (int k = 0; k < D_DIM; k += KU) {
        const int cur = (k >> 3) & 1;
        const int nxt = cur ^ 1;
        if (k + KU < D_DIM) {
            #pragma unroll
            for (int u = 0; u < KU; u++)
                wr[nxt][u] = wp[(size_t)(k + KU + u) * E_DIM];
        }
        #pragma unroll
        for (int r = 0; r < RPW; r++) {
            const float* xp = xb + (size_t)r * D_DIM + k;   // wave-uniform -> s_load
            #pragma unroll
            for (int u = 0; u < KU; u++)
                acc[r] = fmaf(xp[u], wr[cur][u], acc[r]);
        }
    }

    const float bv = bias[lane];

    #pragma unroll
    for (int r = 0; r < RPW; r++) {
        const float l = acc[r] + bv;

        // wave-wide softmax (width 64)
        float mx = l;
        #pragma unroll
        for (int off = 32; off; off >>= 1)
            mx = fmaxf(mx, __shfl_xor(mx, off, 64));
        const float e = expf(l - mx);
        float s = e;
        #pragma unroll
        for (int off = 32; off; off >>= 1)
            s += __shfl_xor(s, off, 64);
        const float p = e / s;   // p > 0, finite

        // top-1: pack (prob bits, 63-lane) so ties pick the LOWEST lane (jax semantics)
        const unsigned long long key0 =
            ((unsigned long long)__float_as_uint(p) << 32) | (unsigned long long)(63 - lane);
        unsigned long long k1 = key0;
        #pragma unroll
        for (int off = 32; off; off >>= 1) {
            unsigned long long o = __shfl_xor(k1, off, 64);
            k1 = (o > k1) ? o : k1;
        }
        const int   i1 = 63 - (int)(k1 & 0xFFFFFFFFull);
        const float v1 = __uint_as_float((unsigned)(k1 >> 32));

        // top-2: mask out winner, reduce again
        unsigned long long k2 = (lane == i1) ? 0ull : key0;
        #pragma unroll
        for (int off = 32; off; off >>= 1) {
            unsigned long long o = __shfl_xor(k2, off, 64);
            k2 = (o > k2) ? o : k2;
        }
        const int   i2 = 63 - (int)(k2 & 0xFFFFFFFFull);
        const float v2 = __uint_as_float((unsigned)(k2 >> 32));

        if (lane == 0) {
            const int gr = row0 + r;
            out[gr * 2 + 0] = (float)i1;
            out[gr * 2 + 1] = (float)i2;
            out[M_DIM * 2 + gr * 2 + 0] = v1;
            out[M_DIM * 2 + gr * 2 + 1] = v2;
        }
    }
}

extern "C" void kernel_launch(void* const* d_in, const int* in_sizes, int n_in,
                              void* d_out, int out_size, void* d_ws, size_t ws_size,
                              hipStream_t stream) {
    const float* x  = (const float*)d_in[0];
    const float* Wm = (const float*)d_in[1];
    const float* b  = (const float*)d_in[2];
    float* out = (float*)d_out;

    dim3 grid(M_DIM / (RPW * WPB));   // 512 blocks
    dim3 block(64 * WPB);             // 256 threads = 4 waves
    topk_router_kernel<<<grid, block, 0, stream>>>(x, Wm, b, out);
}

// Round 3
// 650.462 us; speedup vs baseline: 1.1672x; 1.1672x over previous
//
#include <hip/hip_runtime.h>
#include <math.h>

// TopKRouter: logits = x(16384x2048) @ W(2048x64) + b; softmax E=64; top-2.
// Output: d_out[0:32768] = indices (as float), d_out[32768:65536] = probs.
//
// Structure: no LDS. 256 threads = 16 expert-cols (4 experts each) x 16 row
// groups (2 rows each) -> BM=32 rows/block, 512 blocks (2/CU, 4 waves/SIMD).
// x: per-thread float4 loads, register double-buffered one KC=16 chunk ahead
// (16 cols issue same addresses -> same cacheline, free). W: per-thread float4
// from global, L1/L2-resident. Latency hidden by TLP (4 waves/SIMD).

#define D_DIM 2048
#define E_DIM 64
#define M_DIM 16384
#define BM 32
#define KC 16

__global__ __launch_bounds__(256, 4) void topk_router_kernel(
    const float* __restrict__ x, const float* __restrict__ Wm,
    const float* __restrict__ bias, float* __restrict__ out)
{
    const int tid  = threadIdx.x;
    const int col  = tid & 15;        // experts col*4 .. col*4+3
    const int rowg = tid >> 4;        // 0..15
    const int r0   = blockIdx.x * BM + rowg * 2;

    const float* xr0 = x + (size_t)r0 * D_DIM;
    const float* xr1 = xr0 + D_DIM;
    const float* wc  = Wm + col * 4;

    float4 a0[4], a1[4], b0[4], b1[4];   // x double buffers: 4 float4 per row
    #pragma unroll
    for (int q = 0; q < 4; q++) {
        a0[q] = *reinterpret_cast<const float4*>(xr0 + q * 4);
        a1[q] = *reinterpret_cast<const float4*>(xr1 + q * 4);
    }

    float acc00 = 0.f, acc01 = 0.f, acc02 = 0.f, acc03 = 0.f;
    float acc10 = 0.f, acc11 = 0.f, acc12 = 0.f, acc13 = 0.f;

    #pragma unroll 1
    for (int k0 = 0; k0 < D_DIM; k0 += 2 * KC) {
        // ---- half A: prefetch chunk k0+KC into b*, compute k0..k0+KC-1 from a*
        {
            const int kp = k0 + KC;
            #pragma unroll
            for (int q = 0; q < 4; q++) {
                b0[q] = *reinterpret_cast<const float4*>(xr0 + kp + q * 4);
                b1[q] = *reinterpret_cast<const float4*>(xr1 + kp + q * 4);
            }
            #pragma unroll
            for (int q = 0; q < 4; q++) {
                const float xq0[4] = {a0[q].x, a0[q].y, a0[q].z, a0[q].w};
                const float xq1[4] = {a1[q].x, a1[q].y, a1[q].z, a1[q].w};
                #pragma unroll
                for (int j = 0; j < 4; j++) {
                    const float4 w = *reinterpret_cast<const float4*>(
                        wc + (size_t)(k0 + q * 4 + j) * E_DIM);
                    acc00 = fmaf(xq0[j], w.x, acc00);
                    acc01 = fmaf(xq0[j], w.y, acc01);
                    acc02 = fmaf(xq0[j], w.z, acc02);
                    acc03 = fmaf(xq0[j], w.w, acc03);
                    acc10 = fmaf(xq1[j], w.x, acc10);
                    acc11 = fmaf(xq1[j], w.y, acc11);
                    acc12 = fmaf(xq1[j], w.z, acc12);
                    acc13 = fmaf(xq1[j], w.w, acc13);
                }
            }
        }
        // ---- half B: prefetch chunk k0+2*KC into a* (clamped), compute from b*
        {
            const int kc = k0 + KC;
            int kp = k0 + 2 * KC;
            if (kp > D_DIM - KC) kp = D_DIM - KC;   // last-iter clamp (result unused)
            #pragma unroll
            for (int q = 0; q < 4; q++) {
                a0[q] = *reinterpret_cast<const float4*>(xr0 + kp + q * 4);
                a1[q] = *reinterpret_cast<const float4*>(xr1 + kp + q * 4);
            }
            #pragma unroll
            for (int q = 0; q < 4; q++) {
                const float xq0[4] = {b0[q].x, b0[q].y, b0[q].z, b0[q].w};
                const float xq1[4] = {b1[q].x, b1[q].y, b1[q].z, b1[q].w};
                #pragma unroll
                for (int j = 0; j < 4; j++) {
                    const float4 w = *reinterpret_cast<const float4*>(
                        wc + (size_t)(kc + q * 4 + j) * E_DIM);
                    acc00 = fmaf(xq0[j], w.x, acc00);
                    acc01 = fmaf(xq0[j], w.y, acc01);
                    acc02 = fmaf(xq0[j], w.z, acc02);
                    acc03 = fmaf(xq0[j], w.w, acc03);
                    acc10 = fmaf(xq1[j], w.x, acc10);
                    acc11 = fmaf(xq1[j], w.y, acc11);
                    acc12 = fmaf(xq1[j], w.z, acc12);
                    acc13 = fmaf(xq1[j], w.w, acc13);
                }
            }
        }
    }

    // ---- epilogue: softmax + top-2 per row, reduced across the 16-lane group
    // (lanes sharing lane>>4; xor offsets 1,2,4,8 stay inside the group).
    const float4 bv = *reinterpret_cast<const float4*>(bias + col * 4);

    #pragma unroll
    for (int r = 0; r < 2; r++) {
        float l0 = (r ? acc10 : acc00) + bv.x;
        float l1 = (r ? acc11 : acc01) + bv.y;
        float l2 = (r ? acc12 : acc02) + bv.z;
        float l3 = (r ? acc13 : acc03) + bv.w;

        float m = fmaxf(fmaxf(l0, l1), fmaxf(l2, l3));
        #pragma unroll
        for (int off = 1; off < 16; off <<= 1)
            m = fmaxf(m, __shfl_xor(m, off, 64));

        const float e0 = expf(l0 - m), e1 = expf(l1 - m);
        const float e2 = expf(l2 - m), e3 = expf(l3 - m);
        float s = e0 + e1 + e2 + e3;
        #pragma unroll
        for (int off = 1; off < 16; off <<= 1)
            s += __shfl_xor(s, off, 64);

        const float p0 = e0 / s, p1 = e1 / s, p2 = e2 / s, p3 = e3 / s;

        // keys: (prob bits << 32) | (63 - expert)  -> ties pick lowest index
        const int eb = col * 4;
        const unsigned long long ka =
            ((unsigned long long)__float_as_uint(p0) << 32) | (unsigned long long)(63 - eb);
        const unsigned long long kb =
            ((unsigned long long)__float_as_uint(p1) << 32) | (unsigned long long)(62 - eb);
        const unsigned long long kc_ =
            ((unsigned long long)__float_as_uint(p2) << 32) | (unsigned long long)(61 - eb);
        const unsigned long long kd =
            ((unsigned long long)__float_as_uint(p3) << 32) | (unsigned long long)(60 - eb);

        unsigned long long hi1 = ka > kb ? ka : kb, lo1 = ka > kb ? kb : ka;
        unsigned long long hi2 = kc_ > kd ? kc_ : kd, lo2 = kc_ > kd ? kd : kc_;
        unsigned long long k1 = hi1 > hi2 ? hi1 : hi2;
        unsigned long long mn = hi1 > hi2 ? hi2 : hi1;
        unsigned long long mx = lo1 > lo2 ? lo1 : lo2;
        unsigned long long k2 = mn > mx ? mn : mx;

        #pragma unroll
        for (int off = 1; off < 16; off <<= 1) {
            const unsigned long long o1 = __shfl_xor(k1, off, 64);
            const unsigned long long o2 = __shfl_xor(k2, off, 64);
            const unsigned long long n1 = k1 > o1 ? k1 : o1;
            const unsigned long long w1 = k1 > o1 ? o1 : k1;   // loser of firsts
            const unsigned long long w2 = k2 > o2 ? k2 : o2;   // best of seconds
            k1 = n1;
            k2 = w1 > w2 ? w1 : w2;
        }

        if (col == 0) {
            const int gr = r0 + r;
            out[gr * 2 + 0] = (float)(63 - (int)(k1 & 0xFFFFFFFFull));
            out[gr * 2 + 1] = (float)(63 - (int)(k2 & 0xFFFFFFFFull));
            out[M_DIM * 2 + gr * 2 + 0] = __uint_as_float((unsigned)(k1 >> 32));
            out[M_DIM * 2 + gr * 2 + 1] = __uint_as_float((unsigned)(k2 >> 32));
        }
    }
}

extern "C" void kernel_launch(void* const* d_in, const int* in_sizes, int n_in,
                              void* d_out, int out_size, void* d_ws, size_t ws_size,
                              hipStream_t stream) {
    const float* x  = (const float*)d_in[0];
    const float* Wm = (const float*)d_in[1];
    const float* b  = (const float*)d_in[2];
    float* out = (float*)d_out;

    dim3 grid(M_DIM / BM);   // 512 blocks
    dim3 block(256);
    topk_router_kernel<<<grid, block, 0, stream>>>(x, Wm, b, out);
}

// Round 4
// 239.059 us; speedup vs baseline: 3.1759x; 2.7209x over previous
//
#include <hip/hip_runtime.h>
#include <math.h>

// TopKRouter: logits = x(16384x2048) @ W(2048x64) + b; softmax E=64; top-2.
// Output: d_out[0:32768] = indices (as float), d_out[32768:65536] = probs.
//
// fp16 split-3 MFMA path: x = xh + xl*2^-11, W = wh + wl*2^-11 (lo stored
// pre-scaled by 2^11 to stay fp16-normal). logits = xh*wh + 2^-11*(xh*wl' +
// xl'*wh). Residual ~2e-7 — below fp32 reorder noise, index-safe.
// Kernel 1 splits W into transposed fp16 hi/lo in d_ws (512 KB).
// Kernel 2: LDS-free MFMA GEMM; wave = 16 rows x 64 experts; A-frag direct
// from global fp32 (converted in-reg), B-frag contiguous 16B from split-W.

#define D_DIM 2048
#define E_DIM 64
#define M_DIM 16384
#define BK 32
#define NCHUNK (D_DIM / BK)   // 64

typedef _Float16 half8 __attribute__((ext_vector_type(8)));
typedef float floatx4 __attribute__((ext_vector_type(4)));

// ---------------- kernel 1: W split + transpose ----------------
// wsT layout (halves): hi[n][k] at n*D_DIM + k  (n<64), lo at (64+n)*D_DIM + k
__global__ __launch_bounds__(256) void split_w_kernel(
    const float* __restrict__ Wm, _Float16* __restrict__ wsT)
{
    __shared__ float t[64][65];           // [n][k'], padded
    const int tid = threadIdx.x;
    const int k0  = blockIdx.x * 64;

    #pragma unroll
    for (int p = 0; p < 16; p++) {
        int i  = p * 256 + tid;
        int kk = i >> 6, n = i & 63;      // coalesced read of W[k][n]
        t[n][kk] = Wm[(size_t)(k0 + kk) * E_DIM + n];
    }
    __syncthreads();
    #pragma unroll
    for (int p = 0; p < 16; p++) {
        int i  = p * 256 + tid;
        int kk = i & 63, n = i >> 6;      // coalesced write along k
        float v = t[n][kk];
        _Float16 h = (_Float16)v;
        _Float16 l = (_Float16)((v - (float)h) * 2048.0f);
        wsT[(size_t)n * D_DIM + k0 + kk]            = h;
        wsT[(size_t)(E_DIM + n) * D_DIM + k0 + kk]  = l;
    }
}

// ---------------- kernel 2: MFMA GEMM + softmax + top-2 ----------------
__global__ __launch_bounds__(256) void router_mfma_kernel(
    const float* __restrict__ x, const _Float16* __restrict__ wsT,
    const float* __restrict__ bias, float* __restrict__ out)
{
    const int lane = threadIdx.x & 63;
    const int wave = threadIdx.x >> 6;
    const int c    = lane & 15;
    const int quad = lane >> 4;
    const int r0   = blockIdx.x * 64 + wave * 16;

    // A-frag source: lane's row = r0 + c, k = quad*8 + j
    const float* xp = x + (size_t)(r0 + c) * D_DIM + quad * 8;
    // B-frag source: lane's n = c + 16t, k = quad*8 + j (contiguous fp16)
    const _Float16* whp = wsT + (size_t)c * D_DIM + quad * 8;
    const _Float16* wlp = whp + (size_t)E_DIM * D_DIM;

    floatx4 accm[4] = {};   // hi*hi
    floatx4 accl[4] = {};   // hi*lo' + lo'*hi  (scaled by 2^11)

    float4 xs0[2], xs1[2], xs2[2], xs3[2];
    half8  wh0[4], wl0[4], wh1[4], wl1[4];

    auto loadx = [&](int ch, float4* dst) {
        const int kk = ch < NCHUNK ? ch : NCHUNK - 1;   // clamp prefetch tail
        const float* p = xp + kk * BK;
        dst[0] = *reinterpret_cast<const float4*>(p);
        dst[1] = *reinterpret_cast<const float4*>(p + 4);
    };
    auto loadw = [&](int ch, half8* h, half8* l) {
        const int kk = ch < NCHUNK ? ch : NCHUNK - 1;
        #pragma unroll
        for (int t = 0; t < 4; t++) {
            h[t] = *reinterpret_cast<const half8*>(whp + (size_t)t * 16 * D_DIM + kk * BK);
            l[t] = *reinterpret_cast<const half8*>(wlp + (size_t)t * 16 * D_DIM + kk * BK);
        }
    };
    auto compute = [&](const float4* xs, const half8* h, const half8* l) {
        const float xv[8] = {xs[0].x, xs[0].y, xs[0].z, xs[0].w,
                             xs[1].x, xs[1].y, xs[1].z, xs[1].w};
        half8 ah, al;
        #pragma unroll
        for (int j = 0; j < 8; j++) {
            _Float16 hh = (_Float16)xv[j];
            ah[j] = hh;
            al[j] = (_Float16)((xv[j] - (float)hh) * 2048.0f);
        }
        #pragma unroll
        for (int t = 0; t < 4; t++) {
            accm[t] = __builtin_amdgcn_mfma_f32_16x16x32_f16(ah, h[t], accm[t], 0, 0, 0);
            accl[t] = __builtin_amdgcn_mfma_f32_16x16x32_f16(al, h[t], accl[t], 0, 0, 0);
            accl[t] = __builtin_amdgcn_mfma_f32_16x16x32_f16(ah, l[t], accl[t], 0, 0, 0);
        }
    };

    // prologue: x at distance 2, W at distance 1
    loadx(0, xs0); loadx(1, xs1); loadw(0, wh0, wl0);

    #pragma unroll 1
    for (int ch = 0; ch < NCHUNK; ch += 4) {
        loadx(ch + 2, xs2); loadw(ch + 1, wh1, wl1);
        compute(xs0, wh0, wl0);
        loadx(ch + 3, xs3); loadw(ch + 2, wh0, wl0);
        compute(xs1, wh1, wl1);
        loadx(ch + 4, xs0); loadw(ch + 3, wh1, wl1);
        compute(xs2, wh0, wl0);
        loadx(ch + 5, xs1); loadw(ch + 4, wh0, wl0);
        compute(xs3, wh1, wl1);
    }

    // ---- epilogue: C/D layout: row = quad*4 + reg, col = c + 16t ----
    const float scale = 1.0f / 2048.0f;
    float bvt[4];
    #pragma unroll
    for (int t = 0; t < 4; t++) bvt[t] = bias[c + 16 * t];

    #pragma unroll
    for (int i = 0; i < 4; i++) {
        const float l0 = accm[0][i] + accl[0][i] * scale + bvt[0];
        const float l1 = accm[1][i] + accl[1][i] * scale + bvt[1];
        const float l2 = accm[2][i] + accl[2][i] * scale + bvt[2];
        const float l3 = accm[3][i] + accl[3][i] * scale + bvt[3];

        float m = fmaxf(fmaxf(l0, l1), fmaxf(l2, l3));
        #pragma unroll
        for (int off = 1; off < 16; off <<= 1)
            m = fmaxf(m, __shfl_xor(m, off, 64));

        const float e0 = expf(l0 - m), e1 = expf(l1 - m);
        const float e2 = expf(l2 - m), e3 = expf(l3 - m);
        float s = e0 + e1 + e2 + e3;
        #pragma unroll
        for (int off = 1; off < 16; off <<= 1)
            s += __shfl_xor(s, off, 64);

        const float p0 = e0 / s, p1 = e1 / s, p2 = e2 / s, p3 = e3 / s;

        // keys: (prob bits << 32) | (63 - expert); experts c, c+16, c+32, c+48
        const unsigned long long ka =
            ((unsigned long long)__float_as_uint(p0) << 32) | (unsigned long long)(63 - c);
        const unsigned long long kb =
            ((unsigned long long)__float_as_uint(p1) << 32) | (unsigned long long)(47 - c);
        const unsigned long long kc_ =
            ((unsigned long long)__float_as_uint(p2) << 32) | (unsigned long long)(31 - c);
        const unsigned long long kd =
            ((unsigned long long)__float_as_uint(p3) << 32) | (unsigned long long)(15 - c);

        unsigned long long hi1 = ka > kb ? ka : kb, lo1 = ka > kb ? kb : ka;
        unsigned long long hi2 = kc_ > kd ? kc_ : kd, lo2 = kc_ > kd ? kd : kc_;
        unsigned long long k1 = hi1 > hi2 ? hi1 : hi2;
        unsigned long long mn = hi1 > hi2 ? hi2 : hi1;
        unsigned long long mx = lo1 > lo2 ? lo1 : lo2;
        unsigned long long k2 = mn > mx ? mn : mx;

        #pragma unroll
        for (int off = 1; off < 16; off <<= 1) {
            const unsigned long long o1 = __shfl_xor(k1, off, 64);
            const unsigned long long o2 = __shfl_xor(k2, off, 64);
            const unsigned long long n1 = k1 > o1 ? k1 : o1;
            const unsigned long long w1 = k1 > o1 ? o1 : k1;   // loser of firsts
            const unsigned long long w2 = k2 > o2 ? k2 : o2;   // best of seconds
            k1 = n1;
            k2 = w1 > w2 ? w1 : w2;
        }

        if (c == 0) {
            const int gr = r0 + 4 * quad + i;
            out[gr * 2 + 0] = (float)(63 - (int)(k1 & 0xFFFFFFFFull));
            out[gr * 2 + 1] = (float)(63 - (int)(k2 & 0xFFFFFFFFull));
            out[M_DIM * 2 + gr * 2 + 0] = __uint_as_float((unsigned)(k1 >> 32));
            out[M_DIM * 2 + gr * 2 + 1] = __uint_as_float((unsigned)(k2 >> 32));
        }
    }
}

extern "C" void kernel_launch(void* const* d_in, const int* in_sizes, int n_in,
                              void* d_out, int out_size, void* d_ws, size_t ws_size,
                              hipStream_t stream) {
    const float* x  = (const float*)d_in[0];
    const float* Wm = (const float*)d_in[1];
    const float* b  = (const float*)d_in[2];
    float* out = (float*)d_out;
    _Float16* wsT = (_Float16*)d_ws;   // needs 2*64*2048*2 = 512 KB

    split_w_kernel<<<dim3(D_DIM / 64), dim3(256), 0, stream>>>(Wm, wsT);
    router_mfma_kernel<<<dim3(M_DIM / 64), dim3(256), 0, stream>>>(x, wsT, b, out);
}